// Round 3
// baseline (511.602 us; speedup 1.0000x reference)
//
#include <hip/hip_runtime.h>
#include <math.h>

// Problem constants (from reference setup_inputs)
#define HH 1024
#define WW 1024
#define BB 4
#define CC 8   // spin channels; channel 8 of x is the b-field

typedef float v4f __attribute__((ext_vector_type(4)));

// Exact-f64 flip decision, fast-pathed through f32 exp with a certified band.
//
// Reference (numpy f64): de = (2.0*s)*Js ; p = (de<=0) ? 1 : exp(-de*b);
// flip iff (rand < p) && dropout.
//
// Fast path: argf = s*tt where tt = -2*(float)(Js*b)  (reassociated; total
// relative error vs the original-order f64 arg is <= ~1.2e-7, plus __expf's
// |arg|*6e-8 + 1 ulp). Certified band: err = (|argf|*6e-7 + 2e-6)*pe — >3x
// the true bound. rand outside [pe-err, pe+err] -> f32 decision provably
// equals the f64 one. Ambiguous lanes (~1e-5, incl. rand==0 / p-underflow
// edges by construction) recompute the ORIGINAL f64 expression order.
//
// Sign test (de<=0): s*(float)Js <= 0 is decision-equivalent — it can only
// disagree with the f64 sign when |de| < ~1e-40, where p==1 to within 1e-38
// and every representable rand < p, so both paths flip.
__device__ __forceinline__ float decide(float s, float tt, float Jsf, double Js,
                                        float bb, float r, bool keep) {
    const float argf = s * tt;               // ~ -(2 s Js) b
    bool flip;
    if ((s * Jsf <= 0.0f) | (argf >= 0.0f)) {
        flip = true;                          // de<=0 or p>=1: rand in [0,1) < p
    } else {
        const float pe  = __expf(argf);
        const float err = fmaf(fabsf(argf), 6.0e-7f, 2.0e-6f) * pe;
        if (r < pe - err)      flip = true;
        else if (r > pe + err) flip = false;
        else {                                // rare exact path, original order
            double de = (2.0 * (double)s) * Js;
            flip = (de <= 0.0) || ((double)r < exp(-de * (double)bb));
        }
    }
    return (flip & keep) ? -s : s;
}

__global__ __launch_bounds__(256, 6) void ising_sweep(
    const float* __restrict__ x,
    const float* __restrict__ rnd,
    const float* __restrict__ drop,
    float* __restrict__ out)
{
    const int i    = blockIdx.x;          // row
    const int b    = blockIdx.y;          // batch
    const int t    = threadIdx.x;
    const int j0   = t * 4;               // 4 pixels per thread along W
    const int lane = t & 63;

    const int im1 = (i == 0)      ? (HH - 1) : (i - 1);
    const int ip1 = (i == HH - 1) ? 0        : (i + 1);
    const int jl  = (j0 == 0)      ? (WW - 1) : (j0 - 1);
    const int jr  = (j0 + 4 == WW) ? 0        : (j0 + 4);
    const bool edge = (lane == 0) | (lane == 63);   // wave-boundary fixup lanes
    const int  je   = (lane == 0) ? jl : jr;

    const size_t plane = (size_t)HH * WW;
    const float* xb = x + (size_t)b * 9 * plane;
    const size_t rowu = (size_t)im1 * WW + j0;
    const size_t rowd = (size_t)ip1 * WW + j0;
    const size_t rowc = (size_t)i   * WW + j0;
    const size_t rowe = (size_t)i   * WW + je;

    // Center values stay in registers end-to-end (reloading them in the
    // decide loop missed L2 in round 2: +128 MB HBM fetch).
    v4f sreg[CC];
    double Jx = 0.0, Jy = 0.0, Jz = 0.0, Jw = 0.0;

    #pragma unroll
    for (int c = 0; c < CC; ++c) {
        const float* xc = xb + (size_t)c * plane;
        const v4f up = *(const v4f*)(xc + rowu);
        const v4f dn = *(const v4f*)(xc + rowd);
        const v4f ce = *(const v4f*)(xc + rowc);
        sreg[c] = ce;
        // Halo from neighbor lanes (bit-identical to a global load of s[j0-1]/s[j0+4]).
        float lf = __shfl_up(ce.w, 1);
        float rt = __shfl_down(ce.x, 1);
        if (edge) {                      // 2 active lanes: cross-wave / row-wrap fixup
            const float ev = xc[rowe];
            if (lane == 0) lf = ev; else rt = ev;
        }
        // f64 accumulation, SAME expression order as the verified baseline
        Jx += (double)up.x + (double)lf   + (double)ce.y + (double)dn.x;
        Jy += (double)up.y + (double)ce.x + (double)ce.z + (double)dn.y;
        Jz += (double)up.z + (double)ce.y + (double)ce.w + (double)dn.z;
        Jw += (double)up.w + (double)ce.z + (double)rt   + (double)dn.w;
    }

    const v4f bv = *(const v4f*)(xb + (size_t)8 * plane + rowc);
    const v4f dr = *(const v4f*)(drop + rowc);
    const bool kx = dr.x > 0.5f, ky = dr.y > 0.5f, kz = dr.z > 0.5f, kw = dr.w > 0.5f;

    // Per-pixel hoists for the f32 fast path (fallback keeps full-f64 Js).
    const float ttx = -2.0f * (float)(Jx * (double)bv.x);
    const float tty = -2.0f * (float)(Jy * (double)bv.y);
    const float ttz = -2.0f * (float)(Jz * (double)bv.z);
    const float ttw = -2.0f * (float)(Jw * (double)bv.w);
    const float Jxf = (float)Jx, Jyf = (float)Jy, Jzf = (float)Jz, Jwf = (float)Jw;

    const float* rb = rnd + (size_t)b * CC * plane;
    float*       ob = out + (size_t)b * 9 * plane;

    #pragma unroll
    for (int c = 0; c < CC; ++c) {
        // rnd is a read-once stream: nt load keeps it out of L2 (stores stay cached!)
        const v4f rv = __builtin_nontemporal_load((const v4f*)(rb + (size_t)c * plane + rowc));
        const v4f sv = sreg[c];
        v4f o;
        o.x = decide(sv.x, ttx, Jxf, Jx, bv.x, rv.x, kx);
        o.y = decide(sv.y, tty, Jyf, Jy, bv.y, rv.y, ky);
        o.z = decide(sv.z, ttz, Jzf, Jz, bv.z, rv.z, kz);
        o.w = decide(sv.w, ttw, Jwf, Jw, bv.w, rv.w, kw);
        *(v4f*)(ob + (size_t)c * plane + rowc) = o;
    }
    // b-field channel passes through unchanged
    *(v4f*)(ob + (size_t)8 * plane + rowc) = bv;
}

extern "C" void kernel_launch(void* const* d_in, const int* in_sizes, int n_in,
                              void* d_out, int out_size, void* d_ws, size_t ws_size,
                              hipStream_t stream) {
    const float* x    = (const float*)d_in[0];
    const float* rnd  = (const float*)d_in[1];
    const float* drop = (const float*)d_in[2];
    // d_in[3] = nn_kernel: fixed plus-stencil, structure baked into the kernel
    float* out = (float*)d_out;

    dim3 grid(HH, BB);
    dim3 block(WW / 4);
    ising_sweep<<<grid, block, 0, stream>>>(x, rnd, drop, out);
}

// Round 5
// 405.220 us; speedup vs baseline: 1.2625x; 1.2625x over previous
//
#include <hip/hip_runtime.h>
#include <math.h>

// Problem constants (from reference setup_inputs)
#define HH 1024
#define WW 1024
#define BB 4
#define CC 8   // spin channels; channel 8 of x is the b-field

typedef float v2f __attribute__((ext_vector_type(2)));

// Exact-f64 flip decision, fast-pathed through f32 exp with a certified band.
// (Verified absmax==0.0 in rounds 2 and 3.)
//
// Reference (numpy f64): de = (2.0*s)*Js ; p = (de<=0) ? 1 : exp(-de*b);
// flip iff (rand < p) && dropout.
//
// Fast path: argf = s*tt where tt = -2*(float)(Js*b). Certified band:
// err = (|argf|*6e-7 + 2e-6)*pe — >3x the true error bound (f64->f32 cvt,
// reassociation, 1-ulp v_exp_f32). rand outside [pe-err, pe+err] -> f32
// decision provably equals the f64 one. Ambiguous lanes (~1e-5, incl.
// rand==0 / p-underflow edges by construction) recompute the ORIGINAL f64
// expression order. Sign test s*Jsf<=0 is decision-equivalent (can only
// disagree where |de|<~1e-40, where p==1 to 1e-38 and both paths flip).
__device__ __forceinline__ float decide(float s, float tt, float Jsf, double Js,
                                        float bb, float r, bool keep) {
    const float argf = s * tt;               // ~ -(2 s Js) b
    bool flip;
    if ((s * Jsf <= 0.0f) | (argf >= 0.0f)) {
        flip = true;                          // de<=0 or p>=1: rand in [0,1) < p
    } else {
        const float pe  = __expf(argf);
        const float err = fmaf(fabsf(argf), 6.0e-7f, 2.0e-6f) * pe;
        if (r < pe - err)      flip = true;
        else if (r > pe + err) flip = false;
        else {                                // rare exact path, original order
            double de = (2.0 * (double)s) * Js;
            flip = (de <= 0.0) || ((double)r < exp(-de * (double)bb));
        }
    }
    return (flip & keep) ? -s : s;
}

// 2 pixels per thread: halves all persistent per-thread state vs the 4-pixel
// version (sreg 32->16 VGPR, Js 8->4, hoists 12->6) so the s values genuinely
// fit in registers at 8 waves/SIMD — no remat reloads (round-2/3's +358 MB
// fetch + RMW write amplification), no spills.
__global__ __launch_bounds__(256, 8) void ising_sweep(
    const float* __restrict__ x,
    const float* __restrict__ rnd,
    const float* __restrict__ drop,
    float* __restrict__ out)
{
    const int bx   = blockIdx.x;
    const int i    = bx >> 1;             // row; adjacent blocks share a row (L2)
    const int hf   = bx & 1;              // which half of the row
    const int b    = blockIdx.y;          // batch
    const int t    = threadIdx.x;
    const int lane = t & 63;
    const int j0   = (hf * 256 + t) * 2;  // 2 pixels per thread along W

    const int im1 = (i == 0)      ? (HH - 1) : (i - 1);
    const int ip1 = (i == HH - 1) ? 0        : (i + 1);
    const int jl  = (j0 == 0)      ? (WW - 1) : (j0 - 1);
    const int jr  = (j0 + 2 == WW) ? 0        : (j0 + 2);
    const bool edge = (lane == 0) | (lane == 63);   // wave-boundary fixup lanes
    const int  je   = (lane == 0) ? jl : jr;

    const size_t plane = (size_t)HH * WW;
    const float* xb = x + (size_t)b * 9 * plane;
    const size_t rowu = (size_t)im1 * WW + j0;
    const size_t rowd = (size_t)ip1 * WW + j0;
    const size_t rowc = (size_t)i   * WW + j0;
    const size_t rowe = (size_t)i   * WW + je;

    v2f sreg[CC];
    double Jx = 0.0, Jy = 0.0;

    #pragma unroll
    for (int c = 0; c < CC; ++c) {
        const float* xc = xb + (size_t)c * plane;
        const v2f up = *(const v2f*)(xc + rowu);
        const v2f dn = *(const v2f*)(xc + rowd);
        const v2f ce = *(const v2f*)(xc + rowc);
        sreg[c] = ce;
        // Halo from neighbor lanes (bit-identical to loading s[j0-1]/s[j0+2]).
        float lf = __shfl_up(ce.y, 1);
        float rt = __shfl_down(ce.x, 1);
        if (edge) {                      // 2 active lanes: cross-wave / row-wrap fixup
            const float ev = xc[rowe];
            if (lane == 0) lf = ev; else rt = ev;
        }
        // f64 accumulation, SAME positional order as the verified baseline:
        // (((J + up) + left) + right/center) + down
        Jx += (double)up.x + (double)lf   + (double)ce.y + (double)dn.x;
        Jy += (double)up.y + (double)ce.x + (double)rt   + (double)dn.y;
    }

    const v2f bv = *(const v2f*)(xb + (size_t)8 * plane + rowc);
    const v2f dr = *(const v2f*)(drop + rowc);
    const bool kx = dr.x > 0.5f, ky = dr.y > 0.5f;

    // Per-pixel hoists for the f32 fast path (fallback keeps full-f64 Js).
    const float ttx = -2.0f * (float)(Jx * (double)bv.x);
    const float tty = -2.0f * (float)(Jy * (double)bv.y);
    const float Jxf = (float)Jx, Jyf = (float)Jy;

    const float* rb = rnd + (size_t)b * CC * plane;
    float*       ob = out + (size_t)b * 9 * plane;

    #pragma unroll
    for (int c = 0; c < CC; ++c) {
        const v2f rv = *(const v2f*)(rb + (size_t)c * plane + rowc);
        const v2f sv = sreg[c];
        v2f o;
        o.x = decide(sv.x, ttx, Jxf, Jx, bv.x, rv.x, kx);
        o.y = decide(sv.y, tty, Jyf, Jy, bv.y, rv.y, ky);
        *(v2f*)(ob + (size_t)c * plane + rowc) = o;
    }
    // b-field channel passes through unchanged
    *(v2f*)(ob + (size_t)8 * plane + rowc) = bv;
}

extern "C" void kernel_launch(void* const* d_in, const int* in_sizes, int n_in,
                              void* d_out, int out_size, void* d_ws, size_t ws_size,
                              hipStream_t stream) {
    const float* x    = (const float*)d_in[0];
    const float* rnd  = (const float*)d_in[1];
    const float* drop = (const float*)d_in[2];
    // d_in[3] = nn_kernel: fixed plus-stencil, structure baked into the kernel
    float* out = (float*)d_out;

    dim3 grid(HH * 2, BB);
    dim3 block(256);
    ising_sweep<<<grid, block, 0, stream>>>(x, rnd, drop, out);
}